// Round 5
// baseline (1841.693 us; speedup 1.0000x reference)
//
#include <hip/hip_runtime.h>

#define NV 100000
#define NC 100000
#define NSOC 20000
#define NVS (NV + NSOC)
#define EVC 2000000
#define ESC 300000
#define H 64

constexpr int BSH = 7;       // 128 nodes per bucket
constexpr int NBMAX = 1024;  // max buckets
constexpr int EPB = 8192;    // edges per block in bucket passes

// ---------------------------------------------------------------------------
// LDS-tiled fused GEMM:
//   out[n][j] = act( s1*(dot(X1[n],W1[:,j]) + bias[j]) + [NSEC] dot(X2[n],W2[:,j]) )
// Block = 4 waves; TR-row X tile staged in LDS; lane = output col; W in VGPRs.
// K1==H path: 4-row ILP (16 independent FMA chains).
// ---------------------------------------------------------------------------
template<int K1, int NSEC, bool RELU, int TR>
__global__ __launch_bounds__(256) void gemm_lds(
    const float* __restrict__ X1, const float* __restrict__ W1,
    const float* __restrict__ X2, const float* __restrict__ W2,
    const float* __restrict__ bias, float* __restrict__ out,
    int N, float s1)
{
  __shared__ __align__(16) float sx1[TR * K1];
  __shared__ __align__(16) float sx2[NSEC ? TR * H : 4];

  const int n0 = blockIdx.x * TR;

  if constexpr ((K1 & 3) == 0) {
    const float4* X4 = reinterpret_cast<const float4*>(X1);
    float4* S4 = reinterpret_cast<float4*>(sx1);
    const long base4 = (long)n0 * K1 / 4;
    const long lim4 = (long)N * K1 / 4;
    for (int i = threadIdx.x; i < TR * K1 / 4; i += 256)
      S4[i] = (base4 + i < lim4) ? X4[base4 + i] : make_float4(0.f, 0.f, 0.f, 0.f);
  } else {
    const long base = (long)n0 * K1;
    const long lim = (long)N * K1;
    for (int i = threadIdx.x; i < TR * K1; i += 256)
      sx1[i] = (base + i < lim) ? X1[base + i] : 0.f;
  }
  if constexpr (NSEC) {
    const float4* X4 = reinterpret_cast<const float4*>(X2);
    float4* S4 = reinterpret_cast<float4*>(sx2);
    const long base4 = (long)n0 * H / 4;
    const long lim4 = (long)N * H / 4;
    for (int i = threadIdx.x; i < TR * H / 4; i += 256)
      S4[i] = (base4 + i < lim4) ? X4[base4 + i] : make_float4(0.f, 0.f, 0.f, 0.f);
  }
  __syncthreads();

  const int lane = threadIdx.x & 63;
  const int wv = threadIdx.x >> 6;

  float w1[K1];
#pragma unroll
  for (int k = 0; k < K1; ++k) w1[k] = W1[k * H + lane];
  float w2[NSEC ? H : 1];
  if constexpr (NSEC) {
#pragma unroll
    for (int k = 0; k < H; ++k) w2[k] = W2[k * H + lane];
  }
  const float bj = bias[lane];

  constexpr int RPW = TR / 4;
  const int r0 = wv * RPW;

  if constexpr (K1 == H) {
    const float4* sx4 = reinterpret_cast<const float4*>(sx1);
    for (int i = 0; i < RPW; i += 4) {
      float a[4][4];
#pragma unroll
      for (int r = 0; r < 4; ++r)
#pragma unroll
        for (int c = 0; c < 4; ++c) a[r][c] = 0.f;
#pragma unroll
      for (int k4 = 0; k4 < H / 4; ++k4) {
        float4 xr[4];
#pragma unroll
        for (int r = 0; r < 4; ++r) xr[r] = sx4[(r0 + i + r) * (H / 4) + k4];
#pragma unroll
        for (int r = 0; r < 4; ++r) {
          a[r][0] = fmaf(xr[r].x, w1[4 * k4 + 0], a[r][0]);
          a[r][1] = fmaf(xr[r].y, w1[4 * k4 + 1], a[r][1]);
          a[r][2] = fmaf(xr[r].z, w1[4 * k4 + 2], a[r][2]);
          a[r][3] = fmaf(xr[r].w, w1[4 * k4 + 3], a[r][3]);
        }
      }
      float acc[4];
#pragma unroll
      for (int r = 0; r < 4; ++r)
        acc[r] = s1 * (((a[r][0] + a[r][1]) + (a[r][2] + a[r][3])) + bj);

      if constexpr (NSEC) {
        const float4* sy4 = reinterpret_cast<const float4*>(sx2);
        float b[4][4];
#pragma unroll
        for (int r = 0; r < 4; ++r)
#pragma unroll
          for (int c = 0; c < 4; ++c) b[r][c] = 0.f;
#pragma unroll
        for (int k4 = 0; k4 < H / 4; ++k4) {
          float4 xr[4];
#pragma unroll
          for (int r = 0; r < 4; ++r) xr[r] = sy4[(r0 + i + r) * (H / 4) + k4];
#pragma unroll
          for (int r = 0; r < 4; ++r) {
            b[r][0] = fmaf(xr[r].x, w2[4 * k4 + 0], b[r][0]);
            b[r][1] = fmaf(xr[r].y, w2[4 * k4 + 1], b[r][1]);
            b[r][2] = fmaf(xr[r].z, w2[4 * k4 + 2], b[r][2]);
            b[r][3] = fmaf(xr[r].w, w2[4 * k4 + 3], b[r][3]);
          }
        }
#pragma unroll
        for (int r = 0; r < 4; ++r)
          acc[r] += (b[r][0] + b[r][1]) + (b[r][2] + b[r][3]);
      }

#pragma unroll
      for (int r = 0; r < 4; ++r) {
        if constexpr (RELU) acc[r] = fmaxf(acc[r], 0.f);
        const int n = n0 + r0 + i + r;
        if (n < N) out[(size_t)n * H + lane] = acc[r];
      }
    }
  } else {
    // small-K embedding path
    for (int i = 0; i < RPW; i += 2) {
      const int na = n0 + r0 + i;
      if (na >= N) break;
      const bool wb = (na + 1) < N;
      const float* xa = sx1 + (r0 + i) * K1;
      const float* xb = sx1 + (r0 + i + 1) * K1;
      float accA = 0.f, accB = 0.f;
#pragma unroll
      for (int k = 0; k < K1; ++k) {
        accA = fmaf(xa[k], w1[k], accA);
        accB = fmaf(xb[k], w1[k], accB);
      }
      accA = s1 * (accA + bj);
      accB = s1 * (accB + bj);
      if constexpr (RELU) { accA = fmaxf(accA, 0.f); accB = fmaxf(accB, 0.f); }
      out[(size_t)na * H + lane] = accA;
      if (wb) out[(size_t)(na + 1) * H + lane] = accB;
    }
  }
}

// ---------------------------------------------------------------------------
// Fused output MLP: z1=relu(x@W+b); z2=relu(z1@W+b); out=z2@Wout+bout.
// ---------------------------------------------------------------------------
template<int TR>
__global__ __launch_bounds__(256) void mlp_k(
    const float* __restrict__ X, const float* __restrict__ W,
    const float* __restrict__ bh, const float* __restrict__ Wout,
    const float* __restrict__ bo, float* __restrict__ out, int N)
{
  __shared__ __align__(16) float sx[TR * H];
  __shared__ __align__(16) float sz[4][H];

  const int n0 = blockIdx.x * TR;
  {
    const float4* X4 = reinterpret_cast<const float4*>(X);
    float4* S4 = reinterpret_cast<float4*>(sx);
    const long base4 = (long)n0 * H / 4;
    const long lim4 = (long)N * H / 4;
    for (int i = threadIdx.x; i < TR * H / 4; i += 256)
      S4[i] = (base4 + i < lim4) ? X4[base4 + i] : make_float4(0.f, 0.f, 0.f, 0.f);
  }
  __syncthreads();

  const int lane = threadIdx.x & 63;
  const int wv = threadIdx.x >> 6;
  float w[H];
#pragma unroll
  for (int k = 0; k < H; ++k) w[k] = W[k * H + lane];
  const float bhl = bh[lane];
  const float wo = Wout[lane];
  const float bol = bo[0];

  constexpr int RPW = TR / 4;
  const int r0 = wv * RPW;
  for (int i = 0; i < RPW; ++i) {
    const int n = n0 + r0 + i;
    if (n >= N) break;
    const float4* x4 = reinterpret_cast<const float4*>(sx + (r0 + i) * H);
    float a0 = 0.f, a1 = 0.f, a2 = 0.f, a3 = 0.f;
#pragma unroll
    for (int k4 = 0; k4 < H / 4; ++k4) {
      const float4 v = x4[k4];
      a0 = fmaf(v.x, w[4 * k4 + 0], a0);
      a1 = fmaf(v.y, w[4 * k4 + 1], a1);
      a2 = fmaf(v.z, w[4 * k4 + 2], a2);
      a3 = fmaf(v.w, w[4 * k4 + 3], a3);
    }
    const float z1 = fmaxf((a0 + a1) + (a2 + a3) + bhl, 0.f);
    sz[wv][lane] = z1;
    const float4* z4 = reinterpret_cast<const float4*>(sz[wv]);
    a0 = 0.f; a1 = 0.f; a2 = 0.f; a3 = 0.f;
#pragma unroll
    for (int k4 = 0; k4 < H / 4; ++k4) {
      const float4 v = z4[k4];
      a0 = fmaf(v.x, w[4 * k4 + 0], a0);
      a1 = fmaf(v.y, w[4 * k4 + 1], a1);
      a2 = fmaf(v.z, w[4 * k4 + 2], a2);
      a3 = fmaf(v.w, w[4 * k4 + 3], a3);
    }
    const float z2 = fmaxf((a0 + a1) + (a2 + a3) + bhl, 0.f);
    float v = z2 * wo;
#pragma unroll
    for (int off = 32; off; off >>= 1) v += __shfl_down(v, off);
    if (lane == 0) out[n] = v + bol;
  }
}

// ---------------------------------------------------------------------------
// Bucketed CSR build (5 kernels + shared upfront memset)
// ---------------------------------------------------------------------------
__global__ __launch_bounds__(256) void bhist_k(const int* __restrict__ key,
                                               int* __restrict__ bcnt, int E, int nb) {
  __shared__ int h[NBMAX];
  for (int i = threadIdx.x; i < nb; i += 256) h[i] = 0;
  __syncthreads();
  const int base = blockIdx.x * EPB;
  for (int i = threadIdx.x; i < EPB; i += 256) {
    const int e = base + i;
    if (e < E) atomicAdd(&h[key[e] >> BSH], 1);
  }
  __syncthreads();
  for (int i = threadIdx.x; i < nb; i += 256)
    if (h[i]) atomicAdd(&bcnt[i], h[i]);
}

__global__ __launch_bounds__(1024) void bscan_k(const int* __restrict__ bcnt,
                                                int* __restrict__ bcur, int nb) {
  __shared__ int s[1024];
  const int t = threadIdx.x;
  const int v = (t < nb) ? bcnt[t] : 0;
  s[t] = v;
  __syncthreads();
  for (int off = 1; off < 1024; off <<= 1) {
    int x = (t >= off) ? s[t - off] : 0;
    __syncthreads();
    s[t] += x;
    __syncthreads();
  }
  if (t < nb) bcur[t] = s[t] - v;  // exclusive
}

__global__ __launch_bounds__(256) void bscatter_k(
    const int* __restrict__ key, const int* __restrict__ payload,
    int* __restrict__ bcur, int2* __restrict__ sorted, int E, int nb) {
  __shared__ int h[NBMAX];
  __shared__ int gb[NBMAX];
  __shared__ unsigned short lr[EPB];
  for (int i = threadIdx.x; i < nb; i += 256) h[i] = 0;
  __syncthreads();
  const int base = blockIdx.x * EPB;
  for (int i = threadIdx.x; i < EPB; i += 256) {
    const int e = base + i;
    if (e < E) lr[i] = (unsigned short)atomicAdd(&h[key[e] >> BSH], 1);
  }
  __syncthreads();
  for (int i = threadIdx.x; i < nb; i += 256)
    if (h[i]) gb[i] = atomicAdd(&bcur[i], h[i]);
  __syncthreads();
  for (int i = threadIdx.x; i < EPB; i += 256) {
    const int e = base + i;
    if (e < E) {
      const int k = key[e];
      sorted[gb[k >> BSH] + lr[i]] = make_int2(k, payload[e]);
    }
  }
}

__global__ __launch_bounds__(256) void hist_sorted_k(const int2* __restrict__ sorted,
                                                     int* __restrict__ deg, int E) {
  const int i = blockIdx.x * 256 + threadIdx.x;
  if (i < E) atomicAdd(&deg[sorted[i].x], 1);
}

__global__ __launch_bounds__(256) void fill_sorted_k(
    const int2* __restrict__ sorted, const int* __restrict__ rp,
    int* __restrict__ cur, int* __restrict__ ei, int E) {
  const int i = blockIdx.x * 256 + threadIdx.x;
  if (i < E) {
    const int2 kp = sorted[i];
    const int p = atomicAdd(&cur[kp.x], 1);
    ei[rp[kp.x] + p] = kp.y;
  }
}

// ---------------------------------------------------------------------------
// Node-count exclusive scan -> rowptr
// ---------------------------------------------------------------------------
__global__ __launch_bounds__(256) void scan1_k(const int* __restrict__ deg,
                                               int* __restrict__ bsum, int N) {
  __shared__ int s[256];
  const int t = threadIdx.x;
  const int gi = blockIdx.x * 256 + t;
  s[t] = (gi < N) ? deg[gi] : 0;
  __syncthreads();
  for (int off = 128; off; off >>= 1) {
    if (t < off) s[t] += s[t + off];
    __syncthreads();
  }
  if (t == 0) bsum[blockIdx.x] = s[0];
}

__global__ __launch_bounds__(512) void scan2_k(const int* __restrict__ bsum,
                                               int* __restrict__ bofs, int NB) {
  __shared__ int s[512];
  const int t = threadIdx.x;
  const int v = (t < NB) ? bsum[t] : 0;
  s[t] = v;
  __syncthreads();
  for (int off = 1; off < 512; off <<= 1) {
    int x = (t >= off) ? s[t - off] : 0;
    __syncthreads();
    s[t] += x;
    __syncthreads();
  }
  if (t < NB) bofs[t] = s[t] - v;  // exclusive
}

__global__ __launch_bounds__(256) void scan3_k(const int* __restrict__ deg,
                                               const int* __restrict__ bofs,
                                               int* __restrict__ rp, int N) {
  __shared__ int s[256];
  const int t = threadIdx.x;
  const int gi = blockIdx.x * 256 + t;
  const int v = (gi < N) ? deg[gi] : 0;
  s[t] = v;
  __syncthreads();
  for (int off = 1; off < 256; off <<= 1) {
    int x = (t >= off) ? s[t - off] : 0;
    __syncthreads();
    s[t] += x;
    __syncthreads();
  }
  const int incl = s[t];
  const int base = bofs[blockIdx.x];
  if (gi < N) rp[gi] = base + incl - v;
  if (gi == N - 1) rp[N] = base + incl;
}

// ---------------------------------------------------------------------------
// float4-lane CSR gather max: 16 lanes cover one 256B row; a wave processes
// 4 edges per load instruction, x4 unroll = 16 edges (4KB) in flight.
// ---------------------------------------------------------------------------
__device__ __forceinline__ float4 fmax4(float4 a, float4 b) {
  return make_float4(fmaxf(a.x, b.x), fmaxf(a.y, b.y),
                     fmaxf(a.z, b.z), fmaxf(a.w, b.w));
}

__device__ __forceinline__ float4 xormax(float4 m, int mask) {
  m.x = fmaxf(m.x, __shfl_xor(m.x, mask));
  m.y = fmaxf(m.y, __shfl_xor(m.y, mask));
  m.z = fmaxf(m.z, __shfl_xor(m.z, mask));
  m.w = fmaxf(m.w, __shfl_xor(m.w, mask));
  return m;
}

// returns per-node max (valid in lanes g==0, i.e. lane<16), zero if no edges
__device__ __forceinline__ float4 gmax_csr4(const float4* __restrict__ pooled4,
                                            const int* __restrict__ rp,
                                            const int* __restrict__ ei,
                                            int n, int g, int sub) {
  const int p0 = rp[n], p1 = rp[n + 1];
  float4 z = make_float4(0.f, 0.f, 0.f, 0.f);
  float4 m0 = z, m1 = z, m2 = z, m3 = z;
  if (p1 > p0) {
    const int last = p1 - 1;
    for (int p = p0; p < p1; p += 16) {
      int e0 = p + g;      e0 = e0 <= last ? e0 : last;
      int e1 = p + 4 + g;  e1 = e1 <= last ? e1 : last;
      int e2 = p + 8 + g;  e2 = e2 <= last ? e2 : last;
      int e3 = p + 12 + g; e3 = e3 <= last ? e3 : last;
      const int s0 = ei[e0], s1 = ei[e1], s2 = ei[e2], s3 = ei[e3];
      m0 = fmax4(m0, pooled4[(size_t)s0 * 16 + sub]);
      m1 = fmax4(m1, pooled4[(size_t)s1 * 16 + sub]);
      m2 = fmax4(m2, pooled4[(size_t)s2 * 16 + sub]);
      m3 = fmax4(m3, pooled4[(size_t)s3 * 16 + sub]);
    }
  }
  float4 m = fmax4(fmax4(m0, m1), fmax4(m2, m3));
  m = xormax(m, 16);
  m = xormax(m, 32);
  return m;
}

// forward: out[n] = maxA(pooledA) + maxB(pooledB) over con node n
__global__ __launch_bounds__(256) void gather2_k(
    const float4* __restrict__ pooledA, const int* __restrict__ rpA,
    const int* __restrict__ eiA,
    const float4* __restrict__ pooledB, const int* __restrict__ rpB,
    const int* __restrict__ eiB,
    float4* __restrict__ out, int N)
{
  const int lane = threadIdx.x & 63;
  const int g = lane >> 4, sub = lane & 15;
  const int n = __builtin_amdgcn_readfirstlane(blockIdx.x * 4 + (threadIdx.x >> 6));
  if (n >= N) return;
  const float4 a = gmax_csr4(pooledA, rpA, eiA, n, g, sub);
  const float4 b = gmax_csr4(pooledB, rpB, eiB, n, g, sub);
  if (g == 0)
    out[(size_t)n * 16 + sub] =
        make_float4(a.x + b.x, a.y + b.y, a.z + b.z, a.w + b.w);
}

// backward: node<NV -> var CSR; else soc CSR; both read pooledC
__global__ __launch_bounds__(256) void gatherVS_k(
    const float4* __restrict__ pooledC,
    const int* __restrict__ rpV, const int* __restrict__ eiV,
    const int* __restrict__ rpS, const int* __restrict__ eiS,
    float4* __restrict__ out)
{
  const int lane = threadIdx.x & 63;
  const int g = lane >> 4, sub = lane & 15;
  const int n = __builtin_amdgcn_readfirstlane(blockIdx.x * 4 + (threadIdx.x >> 6));
  if (n >= NVS) return;
  float4 m;
  if (n < NV) m = gmax_csr4(pooledC, rpV, eiV, n, g, sub);
  else        m = gmax_csr4(pooledC, rpS, eiS, n - NV, g, sub);
  if (g == 0) out[(size_t)n * 16 + sub] = m;
}

extern "C" void kernel_launch(void* const* d_in, const int* in_sizes, int n_in,
                              void* d_out, int out_size, void* d_ws, size_t ws_size,
                              hipStream_t stream) {
  const float* var_x = (const float*)d_in[0];
  const float* con_x = (const float*)d_in[1];
  const float* soc_x = (const float*)d_in[2];
  const float* W_var = (const float*)d_in[3];
  const float* b_var = (const float*)d_in[4];
  const float* W_con = (const float*)d_in[5];
  const float* b_con = (const float*)d_in[6];
  const float* W_soc = (const float*)d_in[7];
  const float* b_soc = (const float*)d_in[8];
  const float* L[4][5];  // L[0]=l1f, L[1]=l1b, L[2]=l2f, L[3]=l2b
  for (int l = 0; l < 4; ++l)
    for (int p = 0; p < 5; ++p)
      L[l][p] = (const float*)d_in[9 + l * 5 + p];
  const float* W_hid = (const float*)d_in[29];
  const float* b_hid = (const float*)d_in[30];
  const float* W_out = (const float*)d_in[31];
  const float* b_out = (const float*)d_in[32];
  const int* vc_src = (const int*)d_in[33];
  const int* vc_dst = (const int*)d_in[34];
  const int* sc_src = (const int*)d_in[35];
  const int* sc_dst = (const int*)d_in[36];

  char* ws = (char*)d_ws;
  const size_t F_VS = (size_t)NVS * H * 4;  // 30.72 MB
  const size_t F_C  = (size_t)NC * H * 4;   // 25.6 MB
  float* hvs    = (float*)(ws);
  float* hvs2   = (float*)(ws + F_VS);
  float* h_con  = (float*)(ws + 2 * F_VS);
  float* h_con2 = (float*)(ws + 2 * F_VS + F_C);
  float* pooled = (float*)(ws + 2 * F_VS + 2 * F_C);
  float* agg    = (float*)(ws + 3 * F_VS + 2 * F_C);
  int2*  sorted = (int2*)agg;  // 18.4MB < F_VS; agg dead during builds
  char* csr = ws + 4 * F_VS + 2 * F_C;
  int* rpCv = (int*)(csr);
  int* eiCv = rpCv + (NC + 1);
  int* rpCs = eiCv + EVC;
  int* eiCs = rpCs + (NC + 1);
  int* rpV  = eiCs + ESC;
  int* eiV  = rpV + (NV + 1);
  int* rpS  = eiV + EVC;
  int* eiS  = rpS + (NSOC + 1);
  int* aux  = eiS + ESC;
  // aux: 4 x (deg[100001], cur[100001]) + 4 x bcnt[1024]  -- zeroed by ONE memset
  int* deg[4], *cur[4], *bcnt[4];
  for (int i = 0; i < 4; ++i) {
    deg[i]  = aux + (size_t)i * 2 * 100001;
    cur[i]  = deg[i] + 100001;
    bcnt[i] = aux + 8 * 100001 + i * 1024;
  }
  const size_t aux_zero_bytes = (8ull * 100001 + 4 * 1024) * 4;
  int* bcur = aux + 8 * 100001 + 4 * 1024;
  int* bsum = bcur + 1024;
  int* bofs = bsum + 512;

  constexpr int TR = 64;
  auto grid_l = [](int n) { return dim3((unsigned)((n + TR - 1) / TR)); };
  auto grid_t = [](int n) { return dim3((unsigned)((n + 255) / 256)); };
  auto grid_w = [](int n) { return dim3((unsigned)((n + 3) / 4)); };
  auto grid_b = [](int e) { return dim3((unsigned)((e + EPB - 1) / EPB)); };
  const dim3 B(256);

  float* h_var = hvs;                       // rows [0,NV)
  float* h_soc = hvs + (size_t)NV * H;      // rows [NV,NVS)

  // ---- single memset for all build aux ----------------------------------
  hipMemsetAsync(aux, 0, aux_zero_bytes, stream);

  auto build_csr = [&](const int* key, const int* payload, int E, int Nn,
                       int* rp, int* ei, int bi) {
    const int nb = (Nn + (1 << BSH) - 1) >> BSH;
    const int ns = (Nn + 255) / 256;
    bhist_k<<<grid_b(E), B, 0, stream>>>(key, bcnt[bi], E, nb);
    bscan_k<<<dim3(1), dim3(1024), 0, stream>>>(bcnt[bi], bcur, nb);
    bscatter_k<<<grid_b(E), B, 0, stream>>>(key, payload, bcur, sorted, E, nb);
    hist_sorted_k<<<grid_t(E), B, 0, stream>>>(sorted, deg[bi], E);
    scan1_k<<<dim3((unsigned)ns), B, 0, stream>>>(deg[bi], bsum, Nn);
    scan2_k<<<dim3(1), dim3(512), 0, stream>>>(bsum, bofs, ns);
    scan3_k<<<dim3((unsigned)ns), B, 0, stream>>>(deg[bi], bofs, rp, Nn);
    fill_sorted_k<<<grid_t(E), B, 0, stream>>>(sorted, rp, cur[bi], ei, E);
  };

  // ---- all CSR builds upfront -------------------------------------------
  build_csr(vc_dst, vc_src, EVC, NC, rpCv, eiCv, 0);
  build_csr(sc_dst, sc_src, ESC, NC, rpCs, eiCs, 1);
  build_csr(vc_src, vc_dst, EVC, NV, rpV, eiV, 2);
  build_csr(sc_src, sc_dst, ESC, NSOC, rpS, eiS, 3);

  // ---- embeddings -------------------------------------------------------
  gemm_lds<7, 0, true, TR><<<grid_l(NV), B, 0, stream>>>(var_x, W_var, nullptr, nullptr, b_var, h_var, NV, 1.f);
  gemm_lds<4, 0, true, TR><<<grid_l(NC), B, 0, stream>>>(con_x, W_con, nullptr, nullptr, b_con, h_con, NC, 1.f);
  gemm_lds<6, 0, true, TR><<<grid_l(NSOC), B, 0, stream>>>(soc_x, W_soc, nullptr, nullptr, b_soc, h_soc, NSOC, 1.f);

  // ---- forward half-passes (update constraints) -------------------------
  float* cin = h_con;
  float* cout = h_con2;
  auto fwd_layer = [&](int li) {
    // pooled over var+soc in ONE launch (shared Wp)
    gemm_lds<64, 0, true, TR><<<grid_l(NVS), B, 0, stream>>>(hvs, L[li][0], nullptr, nullptr, L[li][1], pooled, NVS, 1.f);
    gather2_k<<<grid_w(NC), B, 0, stream>>>(
        (const float4*)pooled, rpCv, eiCv,
        (const float4*)(pooled + (size_t)NV * H), rpCs, eiCs,
        (float4*)agg, NC);
    gemm_lds<64, 1, true, TR><<<grid_l(NC), B, 0, stream>>>(cin, L[li][2], agg, L[li][3], L[li][4], cout, NC, 2.f);
    float* t = cin; cin = cout; cout = t;
  };
  fwd_layer(0);  // l1f
  fwd_layer(2);  // l2f

  // ---- backward half-passes (update var & soc from final h_con) ---------
  float* vin = hvs;
  float* vout = hvs2;
  auto bwd_layer = [&](int li) {
    gemm_lds<64, 0, true, TR><<<grid_l(NC), B, 0, stream>>>(cin, L[li][0], nullptr, nullptr, L[li][1], pooled, NC, 1.f);
    gatherVS_k<<<grid_w(NVS), B, 0, stream>>>((const float4*)pooled, rpV, eiV, rpS, eiS, (float4*)agg);
    gemm_lds<64, 1, true, TR><<<grid_l(NVS), B, 0, stream>>>(vin, L[li][2], agg, L[li][3], L[li][4], vout, NVS, 1.f);
    float* t = vin; vin = vout; vout = t;
  };
  bwd_layer(1);  // l1b
  bwd_layer(3);  // l2b

  // ---- fused output MLP over var rows -----------------------------------
  mlp_k<TR><<<grid_l(NV), B, 0, stream>>>(vin, W_hid, b_hid, W_out, b_out, (float*)d_out, NV);
}

// Round 6
// 1092.911 us; speedup vs baseline: 1.6851x; 1.6851x over previous
//
#include <hip/hip_runtime.h>

#define NV 100000
#define NC 100000
#define NSOC 20000
#define NVS (NV + NSOC)
#define EVC 2000000
#define ESC 300000
#define H 64

constexpr int BSH = 7;       // 128 nodes per bucket
constexpr int NBMAX = 1024;  // max buckets
constexpr int EPB = 8192;    // edges per block in bucket passes

// ---------------------------------------------------------------------------
// LDS-tiled fused GEMM:
//   out[n][j] = act( s1*(dot(X1[n],W1[:,j]) + bias[j]) + [NSEC] dot(X2[n],W2[:,j]) )
// Block = 4 waves; TR-row X tile staged in LDS; lane = output col; W in VGPRs.
// 2-row ILP (8 independent FMA chains) -- 4-row spilled (256 VGPR, 479MB
// scratch writes, round-5 regression). Keep VGPR < ~180.
// ---------------------------------------------------------------------------
template<int K1, int NSEC, bool RELU, int TR>
__global__ __launch_bounds__(256) void gemm_lds(
    const float* __restrict__ X1, const float* __restrict__ W1,
    const float* __restrict__ X2, const float* __restrict__ W2,
    const float* __restrict__ bias, float* __restrict__ out,
    int N, float s1)
{
  __shared__ __align__(16) float sx1[TR * K1];
  __shared__ __align__(16) float sx2[NSEC ? TR * H : 4];

  const int n0 = blockIdx.x * TR;

  if constexpr ((K1 & 3) == 0) {
    const float4* X4 = reinterpret_cast<const float4*>(X1);
    float4* S4 = reinterpret_cast<float4*>(sx1);
    const long base4 = (long)n0 * K1 / 4;
    const long lim4 = (long)N * K1 / 4;
    for (int i = threadIdx.x; i < TR * K1 / 4; i += 256)
      S4[i] = (base4 + i < lim4) ? X4[base4 + i] : make_float4(0.f, 0.f, 0.f, 0.f);
  } else {
    const long base = (long)n0 * K1;
    const long lim = (long)N * K1;
    for (int i = threadIdx.x; i < TR * K1; i += 256)
      sx1[i] = (base + i < lim) ? X1[base + i] : 0.f;
  }
  if constexpr (NSEC) {
    const float4* X4 = reinterpret_cast<const float4*>(X2);
    float4* S4 = reinterpret_cast<float4*>(sx2);
    const long base4 = (long)n0 * H / 4;
    const long lim4 = (long)N * H / 4;
    for (int i = threadIdx.x; i < TR * H / 4; i += 256)
      S4[i] = (base4 + i < lim4) ? X4[base4 + i] : make_float4(0.f, 0.f, 0.f, 0.f);
  }
  __syncthreads();

  const int lane = threadIdx.x & 63;
  const int wv = threadIdx.x >> 6;

  float w1[K1];
#pragma unroll
  for (int k = 0; k < K1; ++k) w1[k] = W1[k * H + lane];
  float w2[NSEC ? H : 1];
  if constexpr (NSEC) {
#pragma unroll
    for (int k = 0; k < H; ++k) w2[k] = W2[k * H + lane];
  }
  const float bj = bias[lane];

  constexpr int RPW = TR / 4;
  const int r0 = wv * RPW;

  if constexpr (K1 == H) {
    for (int i = 0; i < RPW; i += 2) {
      const int na = n0 + r0 + i;
      if (na >= N) break;
      const bool wb = (na + 1) < N;

      const float4* xa = reinterpret_cast<const float4*>(sx1 + (r0 + i) * H);
      const float4* xb = reinterpret_cast<const float4*>(sx1 + (r0 + i + 1) * H);
      float a0 = 0.f, a1 = 0.f, a2 = 0.f, a3 = 0.f;
      float b0 = 0.f, b1 = 0.f, b2 = 0.f, b3 = 0.f;
#pragma unroll
      for (int k4 = 0; k4 < H / 4; ++k4) {
        const float4 va = xa[k4];
        const float4 vb = xb[k4];
        a0 = fmaf(va.x, w1[4 * k4 + 0], a0);
        b0 = fmaf(vb.x, w1[4 * k4 + 0], b0);
        a1 = fmaf(va.y, w1[4 * k4 + 1], a1);
        b1 = fmaf(vb.y, w1[4 * k4 + 1], b1);
        a2 = fmaf(va.z, w1[4 * k4 + 2], a2);
        b2 = fmaf(vb.z, w1[4 * k4 + 2], b2);
        a3 = fmaf(va.w, w1[4 * k4 + 3], a3);
        b3 = fmaf(vb.w, w1[4 * k4 + 3], b3);
      }
      float accA = s1 * (((a0 + a1) + (a2 + a3)) + bj);
      float accB = s1 * (((b0 + b1) + (b2 + b3)) + bj);

      if constexpr (NSEC) {
        const float4* ya = reinterpret_cast<const float4*>(sx2 + (r0 + i) * H);
        const float4* yb = reinterpret_cast<const float4*>(sx2 + (r0 + i + 1) * H);
        a0 = 0.f; a1 = 0.f; a2 = 0.f; a3 = 0.f;
        b0 = 0.f; b1 = 0.f; b2 = 0.f; b3 = 0.f;
#pragma unroll
        for (int k4 = 0; k4 < H / 4; ++k4) {
          const float4 va = ya[k4];
          const float4 vb = yb[k4];
          a0 = fmaf(va.x, w2[4 * k4 + 0], a0);
          b0 = fmaf(vb.x, w2[4 * k4 + 0], b0);
          a1 = fmaf(va.y, w2[4 * k4 + 1], a1);
          b1 = fmaf(vb.y, w2[4 * k4 + 1], b1);
          a2 = fmaf(va.z, w2[4 * k4 + 2], a2);
          b2 = fmaf(vb.z, w2[4 * k4 + 2], b2);
          a3 = fmaf(va.w, w2[4 * k4 + 3], a3);
          b3 = fmaf(vb.w, w2[4 * k4 + 3], b3);
        }
        accA += (a0 + a1) + (a2 + a3);
        accB += (b0 + b1) + (b2 + b3);
      }

      if constexpr (RELU) { accA = fmaxf(accA, 0.f); accB = fmaxf(accB, 0.f); }
      out[(size_t)na * H + lane] = accA;
      if (wb) out[(size_t)(na + 1) * H + lane] = accB;
    }
  } else {
    // small-K embedding path
    for (int i = 0; i < RPW; i += 2) {
      const int na = n0 + r0 + i;
      if (na >= N) break;
      const bool wb = (na + 1) < N;
      const float* xa = sx1 + (r0 + i) * K1;
      const float* xb = sx1 + (r0 + i + 1) * K1;
      float accA = 0.f, accB = 0.f;
#pragma unroll
      for (int k = 0; k < K1; ++k) {
        accA = fmaf(xa[k], w1[k], accA);
        accB = fmaf(xb[k], w1[k], accB);
      }
      accA = s1 * (accA + bj);
      accB = s1 * (accB + bj);
      if constexpr (RELU) { accA = fmaxf(accA, 0.f); accB = fmaxf(accB, 0.f); }
      out[(size_t)na * H + lane] = accA;
      if (wb) out[(size_t)(na + 1) * H + lane] = accB;
    }
  }
}

// ---------------------------------------------------------------------------
// Fused output MLP: z1=relu(x@W+b); z2=relu(z1@W+b); out=z2@Wout+bout.
// ---------------------------------------------------------------------------
template<int TR>
__global__ __launch_bounds__(256) void mlp_k(
    const float* __restrict__ X, const float* __restrict__ W,
    const float* __restrict__ bh, const float* __restrict__ Wout,
    const float* __restrict__ bo, float* __restrict__ out, int N)
{
  __shared__ __align__(16) float sx[TR * H];
  __shared__ __align__(16) float sz[4][H];

  const int n0 = blockIdx.x * TR;
  {
    const float4* X4 = reinterpret_cast<const float4*>(X);
    float4* S4 = reinterpret_cast<float4*>(sx);
    const long base4 = (long)n0 * H / 4;
    const long lim4 = (long)N * H / 4;
    for (int i = threadIdx.x; i < TR * H / 4; i += 256)
      S4[i] = (base4 + i < lim4) ? X4[base4 + i] : make_float4(0.f, 0.f, 0.f, 0.f);
  }
  __syncthreads();

  const int lane = threadIdx.x & 63;
  const int wv = threadIdx.x >> 6;
  float w[H];
#pragma unroll
  for (int k = 0; k < H; ++k) w[k] = W[k * H + lane];
  const float bhl = bh[lane];
  const float wo = Wout[lane];
  const float bol = bo[0];

  constexpr int RPW = TR / 4;
  const int r0 = wv * RPW;
  for (int i = 0; i < RPW; ++i) {
    const int n = n0 + r0 + i;
    if (n >= N) break;
    const float4* x4 = reinterpret_cast<const float4*>(sx + (r0 + i) * H);
    float a0 = 0.f, a1 = 0.f, a2 = 0.f, a3 = 0.f;
#pragma unroll
    for (int k4 = 0; k4 < H / 4; ++k4) {
      const float4 v = x4[k4];
      a0 = fmaf(v.x, w[4 * k4 + 0], a0);
      a1 = fmaf(v.y, w[4 * k4 + 1], a1);
      a2 = fmaf(v.z, w[4 * k4 + 2], a2);
      a3 = fmaf(v.w, w[4 * k4 + 3], a3);
    }
    const float z1 = fmaxf((a0 + a1) + (a2 + a3) + bhl, 0.f);
    sz[wv][lane] = z1;
    const float4* z4 = reinterpret_cast<const float4*>(sz[wv]);
    a0 = 0.f; a1 = 0.f; a2 = 0.f; a3 = 0.f;
#pragma unroll
    for (int k4 = 0; k4 < H / 4; ++k4) {
      const float4 v = z4[k4];
      a0 = fmaf(v.x, w[4 * k4 + 0], a0);
      a1 = fmaf(v.y, w[4 * k4 + 1], a1);
      a2 = fmaf(v.z, w[4 * k4 + 2], a2);
      a3 = fmaf(v.w, w[4 * k4 + 3], a3);
    }
    const float z2 = fmaxf((a0 + a1) + (a2 + a3) + bhl, 0.f);
    float v = z2 * wo;
#pragma unroll
    for (int off = 32; off; off >>= 1) v += __shfl_down(v, off);
    if (lane == 0) out[n] = v + bol;
  }
}

// ---------------------------------------------------------------------------
// Bucketed CSR build (5 kernels + shared upfront memset)
// ---------------------------------------------------------------------------
__global__ __launch_bounds__(256) void bhist_k(const int* __restrict__ key,
                                               int* __restrict__ bcnt, int E, int nb) {
  __shared__ int h[NBMAX];
  for (int i = threadIdx.x; i < nb; i += 256) h[i] = 0;
  __syncthreads();
  const int base = blockIdx.x * EPB;
  for (int i = threadIdx.x; i < EPB; i += 256) {
    const int e = base + i;
    if (e < E) atomicAdd(&h[key[e] >> BSH], 1);
  }
  __syncthreads();
  for (int i = threadIdx.x; i < nb; i += 256)
    if (h[i]) atomicAdd(&bcnt[i], h[i]);
}

__global__ __launch_bounds__(1024) void bscan_k(const int* __restrict__ bcnt,
                                                int* __restrict__ bcur, int nb) {
  __shared__ int s[1024];
  const int t = threadIdx.x;
  const int v = (t < nb) ? bcnt[t] : 0;
  s[t] = v;
  __syncthreads();
  for (int off = 1; off < 1024; off <<= 1) {
    int x = (t >= off) ? s[t - off] : 0;
    __syncthreads();
    s[t] += x;
    __syncthreads();
  }
  if (t < nb) bcur[t] = s[t] - v;  // exclusive
}

__global__ __launch_bounds__(256) void bscatter_k(
    const int* __restrict__ key, const int* __restrict__ payload,
    int* __restrict__ bcur, int2* __restrict__ sorted, int E, int nb) {
  __shared__ int h[NBMAX];
  __shared__ int gb[NBMAX];
  __shared__ unsigned short lr[EPB];
  for (int i = threadIdx.x; i < nb; i += 256) h[i] = 0;
  __syncthreads();
  const int base = blockIdx.x * EPB;
  for (int i = threadIdx.x; i < EPB; i += 256) {
    const int e = base + i;
    if (e < E) lr[i] = (unsigned short)atomicAdd(&h[key[e] >> BSH], 1);
  }
  __syncthreads();
  for (int i = threadIdx.x; i < nb; i += 256)
    if (h[i]) gb[i] = atomicAdd(&bcur[i], h[i]);
  __syncthreads();
  for (int i = threadIdx.x; i < EPB; i += 256) {
    const int e = base + i;
    if (e < E) {
      const int k = key[e];
      sorted[gb[k >> BSH] + lr[i]] = make_int2(k, payload[e]);
    }
  }
}

__global__ __launch_bounds__(256) void hist_sorted_k(const int2* __restrict__ sorted,
                                                     int* __restrict__ deg, int E) {
  const int i = blockIdx.x * 256 + threadIdx.x;
  if (i < E) atomicAdd(&deg[sorted[i].x], 1);
}

__global__ __launch_bounds__(256) void fill_sorted_k(
    const int2* __restrict__ sorted, const int* __restrict__ rp,
    int* __restrict__ cur, int* __restrict__ ei, int E) {
  const int i = blockIdx.x * 256 + threadIdx.x;
  if (i < E) {
    const int2 kp = sorted[i];
    const int p = atomicAdd(&cur[kp.x], 1);
    ei[rp[kp.x] + p] = kp.y;
  }
}

// ---------------------------------------------------------------------------
// Node-count exclusive scan -> rowptr
// ---------------------------------------------------------------------------
__global__ __launch_bounds__(256) void scan1_k(const int* __restrict__ deg,
                                               int* __restrict__ bsum, int N) {
  __shared__ int s[256];
  const int t = threadIdx.x;
  const int gi = blockIdx.x * 256 + t;
  s[t] = (gi < N) ? deg[gi] : 0;
  __syncthreads();
  for (int off = 128; off; off >>= 1) {
    if (t < off) s[t] += s[t + off];
    __syncthreads();
  }
  if (t == 0) bsum[blockIdx.x] = s[0];
}

__global__ __launch_bounds__(512) void scan2_k(const int* __restrict__ bsum,
                                               int* __restrict__ bofs, int NB) {
  __shared__ int s[512];
  const int t = threadIdx.x;
  const int v = (t < NB) ? bsum[t] : 0;
  s[t] = v;
  __syncthreads();
  for (int off = 1; off < 512; off <<= 1) {
    int x = (t >= off) ? s[t - off] : 0;
    __syncthreads();
    s[t] += x;
    __syncthreads();
  }
  if (t < NB) bofs[t] = s[t] - v;  // exclusive
}

__global__ __launch_bounds__(256) void scan3_k(const int* __restrict__ deg,
                                               const int* __restrict__ bofs,
                                               int* __restrict__ rp, int N) {
  __shared__ int s[256];
  const int t = threadIdx.x;
  const int gi = blockIdx.x * 256 + t;
  const int v = (gi < N) ? deg[gi] : 0;
  s[t] = v;
  __syncthreads();
  for (int off = 1; off < 256; off <<= 1) {
    int x = (t >= off) ? s[t - off] : 0;
    __syncthreads();
    s[t] += x;
    __syncthreads();
  }
  const int incl = s[t];
  const int base = bofs[blockIdx.x];
  if (gi < N) rp[gi] = base + incl - v;
  if (gi == N - 1) rp[N] = base + incl;
}

// ---------------------------------------------------------------------------
// float4-lane CSR gather max: 16 lanes cover one 256B row; a wave processes
// 4 edges per load instruction, x4 unroll = 16 edges (4KB) in flight.
// ---------------------------------------------------------------------------
__device__ __forceinline__ float4 fmax4(float4 a, float4 b) {
  return make_float4(fmaxf(a.x, b.x), fmaxf(a.y, b.y),
                     fmaxf(a.z, b.z), fmaxf(a.w, b.w));
}

__device__ __forceinline__ float4 xormax(float4 m, int mask) {
  m.x = fmaxf(m.x, __shfl_xor(m.x, mask));
  m.y = fmaxf(m.y, __shfl_xor(m.y, mask));
  m.z = fmaxf(m.z, __shfl_xor(m.z, mask));
  m.w = fmaxf(m.w, __shfl_xor(m.w, mask));
  return m;
}

// returns per-node max (valid in lanes g==0, i.e. lane<16), zero if no edges
__device__ __forceinline__ float4 gmax_csr4(const float4* __restrict__ pooled4,
                                            const int* __restrict__ rp,
                                            const int* __restrict__ ei,
                                            int n, int g, int sub) {
  const int p0 = rp[n], p1 = rp[n + 1];
  float4 z = make_float4(0.f, 0.f, 0.f, 0.f);
  float4 m0 = z, m1 = z, m2 = z, m3 = z;
  if (p1 > p0) {
    const int last = p1 - 1;
    for (int p = p0; p < p1; p += 16) {
      int e0 = p + g;      e0 = e0 <= last ? e0 : last;
      int e1 = p + 4 + g;  e1 = e1 <= last ? e1 : last;
      int e2 = p + 8 + g;  e2 = e2 <= last ? e2 : last;
      int e3 = p + 12 + g; e3 = e3 <= last ? e3 : last;
      const int s0 = ei[e0], s1 = ei[e1], s2 = ei[e2], s3 = ei[e3];
      m0 = fmax4(m0, pooled4[(size_t)s0 * 16 + sub]);
      m1 = fmax4(m1, pooled4[(size_t)s1 * 16 + sub]);
      m2 = fmax4(m2, pooled4[(size_t)s2 * 16 + sub]);
      m3 = fmax4(m3, pooled4[(size_t)s3 * 16 + sub]);
    }
  }
  float4 m = fmax4(fmax4(m0, m1), fmax4(m2, m3));
  m = xormax(m, 16);
  m = xormax(m, 32);
  return m;
}

// forward: out[n] = maxA(pooledA) + maxB(pooledB) over con node n
__global__ __launch_bounds__(256) void gather2_k(
    const float4* __restrict__ pooledA, const int* __restrict__ rpA,
    const int* __restrict__ eiA,
    const float4* __restrict__ pooledB, const int* __restrict__ rpB,
    const int* __restrict__ eiB,
    float4* __restrict__ out, int N)
{
  const int lane = threadIdx.x & 63;
  const int g = lane >> 4, sub = lane & 15;
  const int n = __builtin_amdgcn_readfirstlane(blockIdx.x * 4 + (threadIdx.x >> 6));
  if (n >= N) return;
  const float4 a = gmax_csr4(pooledA, rpA, eiA, n, g, sub);
  const float4 b = gmax_csr4(pooledB, rpB, eiB, n, g, sub);
  if (g == 0)
    out[(size_t)n * 16 + sub] =
        make_float4(a.x + b.x, a.y + b.y, a.z + b.z, a.w + b.w);
}

// backward: node<NV -> var CSR; else soc CSR; both read pooledC
__global__ __launch_bounds__(256) void gatherVS_k(
    const float4* __restrict__ pooledC,
    const int* __restrict__ rpV, const int* __restrict__ eiV,
    const int* __restrict__ rpS, const int* __restrict__ eiS,
    float4* __restrict__ out)
{
  const int lane = threadIdx.x & 63;
  const int g = lane >> 4, sub = lane & 15;
  const int n = __builtin_amdgcn_readfirstlane(blockIdx.x * 4 + (threadIdx.x >> 6));
  if (n >= NVS) return;
  float4 m;
  if (n < NV) m = gmax_csr4(pooledC, rpV, eiV, n, g, sub);
  else        m = gmax_csr4(pooledC, rpS, eiS, n - NV, g, sub);
  if (g == 0) out[(size_t)n * 16 + sub] = m;
}

extern "C" void kernel_launch(void* const* d_in, const int* in_sizes, int n_in,
                              void* d_out, int out_size, void* d_ws, size_t ws_size,
                              hipStream_t stream) {
  const float* var_x = (const float*)d_in[0];
  const float* con_x = (const float*)d_in[1];
  const float* soc_x = (const float*)d_in[2];
  const float* W_var = (const float*)d_in[3];
  const float* b_var = (const float*)d_in[4];
  const float* W_con = (const float*)d_in[5];
  const float* b_con = (const float*)d_in[6];
  const float* W_soc = (const float*)d_in[7];
  const float* b_soc = (const float*)d_in[8];
  const float* L[4][5];  // L[0]=l1f, L[1]=l1b, L[2]=l2f, L[3]=l2b
  for (int l = 0; l < 4; ++l)
    for (int p = 0; p < 5; ++p)
      L[l][p] = (const float*)d_in[9 + l * 5 + p];
  const float* W_hid = (const float*)d_in[29];
  const float* b_hid = (const float*)d_in[30];
  const float* W_out = (const float*)d_in[31];
  const float* b_out = (const float*)d_in[32];
  const int* vc_src = (const int*)d_in[33];
  const int* vc_dst = (const int*)d_in[34];
  const int* sc_src = (const int*)d_in[35];
  const int* sc_dst = (const int*)d_in[36];

  char* ws = (char*)d_ws;
  const size_t F_VS = (size_t)NVS * H * 4;  // 30.72 MB
  const size_t F_C  = (size_t)NC * H * 4;   // 25.6 MB
  float* hvs    = (float*)(ws);
  float* hvs2   = (float*)(ws + F_VS);
  float* h_con  = (float*)(ws + 2 * F_VS);
  float* h_con2 = (float*)(ws + 2 * F_VS + F_C);
  float* pooled = (float*)(ws + 2 * F_VS + 2 * F_C);
  float* agg    = (float*)(ws + 3 * F_VS + 2 * F_C);
  int2*  sorted = (int2*)agg;  // 16MB < F_VS; agg dead during builds
  char* csr = ws + 4 * F_VS + 2 * F_C;
  int* rpCv = (int*)(csr);
  int* eiCv = rpCv + (NC + 1);
  int* rpCs = eiCv + EVC;
  int* eiCs = rpCs + (NC + 1);
  int* rpV  = eiCs + ESC;
  int* eiV  = rpV + (NV + 1);
  int* rpS  = eiV + EVC;
  int* eiS  = rpS + (NSOC + 1);
  int* aux  = eiS + ESC;
  // aux: 4 x (deg[100001], cur[100001]) + 4 x bcnt[1024]  -- zeroed by ONE memset
  int* deg[4], *cur[4], *bcnt[4];
  for (int i = 0; i < 4; ++i) {
    deg[i]  = aux + (size_t)i * 2 * 100001;
    cur[i]  = deg[i] + 100001;
    bcnt[i] = aux + 8 * 100001 + i * 1024;
  }
  const size_t aux_zero_bytes = (8ull * 100001 + 4 * 1024) * 4;
  int* bcur = aux + 8 * 100001 + 4 * 1024;
  int* bsum = bcur + 1024;
  int* bofs = bsum + 512;

  constexpr int TR = 64;
  auto grid_l = [](int n) { return dim3((unsigned)((n + TR - 1) / TR)); };
  auto grid_t = [](int n) { return dim3((unsigned)((n + 255) / 256)); };
  auto grid_w = [](int n) { return dim3((unsigned)((n + 3) / 4)); };
  auto grid_b = [](int e) { return dim3((unsigned)((e + EPB - 1) / EPB)); };
  const dim3 B(256);

  float* h_var = hvs;                       // rows [0,NV)
  float* h_soc = hvs + (size_t)NV * H;      // rows [NV,NVS)

  // ---- single memset for all build aux ----------------------------------
  hipMemsetAsync(aux, 0, aux_zero_bytes, stream);

  auto build_csr = [&](const int* key, const int* payload, int E, int Nn,
                       int* rp, int* ei, int bi) {
    const int nb = (Nn + (1 << BSH) - 1) >> BSH;
    const int ns = (Nn + 255) / 256;
    bhist_k<<<grid_b(E), B, 0, stream>>>(key, bcnt[bi], E, nb);
    bscan_k<<<dim3(1), dim3(1024), 0, stream>>>(bcnt[bi], bcur, nb);
    bscatter_k<<<grid_b(E), B, 0, stream>>>(key, payload, bcur, sorted, E, nb);
    hist_sorted_k<<<grid_t(E), B, 0, stream>>>(sorted, deg[bi], E);
    scan1_k<<<dim3((unsigned)ns), B, 0, stream>>>(deg[bi], bsum, Nn);
    scan2_k<<<dim3(1), dim3(512), 0, stream>>>(bsum, bofs, ns);
    scan3_k<<<dim3((unsigned)ns), B, 0, stream>>>(deg[bi], bofs, rp, Nn);
    fill_sorted_k<<<grid_t(E), B, 0, stream>>>(sorted, rp, cur[bi], ei, E);
  };

  // ---- all CSR builds upfront -------------------------------------------
  build_csr(vc_dst, vc_src, EVC, NC, rpCv, eiCv, 0);
  build_csr(sc_dst, sc_src, ESC, NC, rpCs, eiCs, 1);
  build_csr(vc_src, vc_dst, EVC, NV, rpV, eiV, 2);
  build_csr(sc_src, sc_dst, ESC, NSOC, rpS, eiS, 3);

  // ---- embeddings -------------------------------------------------------
  gemm_lds<7, 0, true, TR><<<grid_l(NV), B, 0, stream>>>(var_x, W_var, nullptr, nullptr, b_var, h_var, NV, 1.f);
  gemm_lds<4, 0, true, TR><<<grid_l(NC), B, 0, stream>>>(con_x, W_con, nullptr, nullptr, b_con, h_con, NC, 1.f);
  gemm_lds<6, 0, true, TR><<<grid_l(NSOC), B, 0, stream>>>(soc_x, W_soc, nullptr, nullptr, b_soc, h_soc, NSOC, 1.f);

  // ---- forward half-passes (update constraints) -------------------------
  float* cin = h_con;
  float* cout = h_con2;
  auto fwd_layer = [&](int li) {
    // pooled over var+soc in ONE launch (shared Wp)
    gemm_lds<64, 0, true, TR><<<grid_l(NVS), B, 0, stream>>>(hvs, L[li][0], nullptr, nullptr, L[li][1], pooled, NVS, 1.f);
    gather2_k<<<grid_w(NC), B, 0, stream>>>(
        (const float4*)pooled, rpCv, eiCv,
        (const float4*)(pooled + (size_t)NV * H), rpCs, eiCs,
        (float4*)agg, NC);
    gemm_lds<64, 1, true, TR><<<grid_l(NC), B, 0, stream>>>(cin, L[li][2], agg, L[li][3], L[li][4], cout, NC, 2.f);
    float* t = cin; cin = cout; cout = t;
  };
  fwd_layer(0);  // l1f
  fwd_layer(2);  // l2f

  // ---- backward half-passes (update var & soc from final h_con) ---------
  float* vin = hvs;
  float* vout = hvs2;
  auto bwd_layer = [&](int li) {
    gemm_lds<64, 0, true, TR><<<grid_l(NC), B, 0, stream>>>(cin, L[li][0], nullptr, nullptr, L[li][1], pooled, NC, 1.f);
    gatherVS_k<<<grid_w(NVS), B, 0, stream>>>((const float4*)pooled, rpV, eiV, rpS, eiS, (float4*)agg);
    gemm_lds<64, 1, true, TR><<<grid_l(NVS), B, 0, stream>>>(vin, L[li][2], agg, L[li][3], L[li][4], vout, NVS, 1.f);
    float* t = vin; vin = vout; vout = t;
  };
  bwd_layer(1);  // l1b
  bwd_layer(3);  // l2b

  // ---- fused output MLP over var rows -----------------------------------
  mlp_k<TR><<<grid_l(NV), B, 0, stream>>>(vin, W_hid, b_hid, W_out, b_out, (float*)d_out, NV);
}

// Round 7
// 832.559 us; speedup vs baseline: 2.2121x; 1.3127x over previous
//
#include <hip/hip_runtime.h>

#define NV 100000
#define NC 100000
#define NSOC 20000
#define NVS (NV + NSOC)
#define EVC 2000000
#define ESC 300000
#define H 64

constexpr int BSH = 7;       // 128 nodes per bucket
constexpr int NBMAX = 1024;  // max buckets
constexpr int EPB = 8192;    // edges per block in bucket passes

// ---------------------------------------------------------------------------
// LDS-tiled fused GEMM (2-row ILP; NO __restrict__ on X1/out: used in-place).
//   out[n][j] = act( s1*(dot(X1[n],W1[:,j]) + bias[j]) + [NSEC] dot(X2[n],W2[:,j]) )
// In-place safe: each block stages its own rows to LDS before overwriting.
// ---------------------------------------------------------------------------
template<int K1, int NSEC, bool RELU, int TR>
__global__ __launch_bounds__(256) void gemm_lds(
    const float* X1, const float* __restrict__ W1,
    const float* __restrict__ X2, const float* __restrict__ W2,
    const float* __restrict__ bias, float* out,
    int N, float s1)
{
  __shared__ __align__(16) float sx1[TR * K1];
  __shared__ __align__(16) float sx2[NSEC ? TR * H : 4];

  const int n0 = blockIdx.x * TR;

  if constexpr ((K1 & 3) == 0) {
    const float4* X4 = reinterpret_cast<const float4*>(X1);
    float4* S4 = reinterpret_cast<float4*>(sx1);
    const long base4 = (long)n0 * K1 / 4;
    const long lim4 = (long)N * K1 / 4;
    for (int i = threadIdx.x; i < TR * K1 / 4; i += 256)
      S4[i] = (base4 + i < lim4) ? X4[base4 + i] : make_float4(0.f, 0.f, 0.f, 0.f);
  } else {
    const long base = (long)n0 * K1;
    const long lim = (long)N * K1;
    for (int i = threadIdx.x; i < TR * K1; i += 256)
      sx1[i] = (base + i < lim) ? X1[base + i] : 0.f;
  }
  if constexpr (NSEC) {
    const float4* X4 = reinterpret_cast<const float4*>(X2);
    float4* S4 = reinterpret_cast<float4*>(sx2);
    const long base4 = (long)n0 * H / 4;
    const long lim4 = (long)N * H / 4;
    for (int i = threadIdx.x; i < TR * H / 4; i += 256)
      S4[i] = (base4 + i < lim4) ? X4[base4 + i] : make_float4(0.f, 0.f, 0.f, 0.f);
  }
  __syncthreads();

  const int lane = threadIdx.x & 63;
  const int wv = threadIdx.x >> 6;

  float w1[K1];
#pragma unroll
  for (int k = 0; k < K1; ++k) w1[k] = W1[k * H + lane];
  float w2[NSEC ? H : 1];
  if constexpr (NSEC) {
#pragma unroll
    for (int k = 0; k < H; ++k) w2[k] = W2[k * H + lane];
  }
  const float bj = bias[lane];

  constexpr int RPW = TR / 4;
  const int r0 = wv * RPW;

  if constexpr (K1 == H) {
    for (int i = 0; i < RPW; i += 2) {
      const int na = n0 + r0 + i;
      if (na >= N) break;
      const bool wb = (na + 1) < N;

      const float4* xa = reinterpret_cast<const float4*>(sx1 + (r0 + i) * H);
      const float4* xb = reinterpret_cast<const float4*>(sx1 + (r0 + i + 1) * H);
      float a0 = 0.f, a1 = 0.f, a2 = 0.f, a3 = 0.f;
      float b0 = 0.f, b1 = 0.f, b2 = 0.f, b3 = 0.f;
#pragma unroll
      for (int k4 = 0; k4 < H / 4; ++k4) {
        const float4 va = xa[k4];
        const float4 vb = xb[k4];
        a0 = fmaf(va.x, w1[4 * k4 + 0], a0);
        b0 = fmaf(vb.x, w1[4 * k4 + 0], b0);
        a1 = fmaf(va.y, w1[4 * k4 + 1], a1);
        b1 = fmaf(vb.y, w1[4 * k4 + 1], b1);
        a2 = fmaf(va.z, w1[4 * k4 + 2], a2);
        b2 = fmaf(vb.z, w1[4 * k4 + 2], b2);
        a3 = fmaf(va.w, w1[4 * k4 + 3], a3);
        b3 = fmaf(vb.w, w1[4 * k4 + 3], b3);
      }
      float accA = s1 * (((a0 + a1) + (a2 + a3)) + bj);
      float accB = s1 * (((b0 + b1) + (b2 + b3)) + bj);

      if constexpr (NSEC) {
        const float4* ya = reinterpret_cast<const float4*>(sx2 + (r0 + i) * H);
        const float4* yb = reinterpret_cast<const float4*>(sx2 + (r0 + i + 1) * H);
        a0 = 0.f; a1 = 0.f; a2 = 0.f; a3 = 0.f;
        b0 = 0.f; b1 = 0.f; b2 = 0.f; b3 = 0.f;
#pragma unroll
        for (int k4 = 0; k4 < H / 4; ++k4) {
          const float4 va = ya[k4];
          const float4 vb = yb[k4];
          a0 = fmaf(va.x, w2[4 * k4 + 0], a0);
          b0 = fmaf(vb.x, w2[4 * k4 + 0], b0);
          a1 = fmaf(va.y, w2[4 * k4 + 1], a1);
          b1 = fmaf(vb.y, w2[4 * k4 + 1], b1);
          a2 = fmaf(va.z, w2[4 * k4 + 2], a2);
          b2 = fmaf(vb.z, w2[4 * k4 + 2], b2);
          a3 = fmaf(va.w, w2[4 * k4 + 3], a3);
          b3 = fmaf(vb.w, w2[4 * k4 + 3], b3);
        }
        accA += (a0 + a1) + (a2 + a3);
        accB += (b0 + b1) + (b2 + b3);
      }

      if constexpr (RELU) { accA = fmaxf(accA, 0.f); accB = fmaxf(accB, 0.f); }
      out[(size_t)na * H + lane] = accA;
      if (wb) out[(size_t)(na + 1) * H + lane] = accB;
    }
  } else {
    for (int i = 0; i < RPW; i += 2) {
      const int na = n0 + r0 + i;
      if (na >= N) break;
      const bool wb = (na + 1) < N;
      const float* xa = sx1 + (r0 + i) * K1;
      const float* xb = sx1 + (r0 + i + 1) * K1;
      float accA = 0.f, accB = 0.f;
#pragma unroll
      for (int k = 0; k < K1; ++k) {
        accA = fmaf(xa[k], w1[k], accA);
        accB = fmaf(xb[k], w1[k], accB);
      }
      accA = s1 * (accA + bj);
      accB = s1 * (accB + bj);
      if constexpr (RELU) { accA = fmaxf(accA, 0.f); accB = fmaxf(accB, 0.f); }
      out[(size_t)na * H + lane] = accA;
      if (wb) out[(size_t)(na + 1) * H + lane] = accB;
    }
  }
}

// ---------------------------------------------------------------------------
// Dual-output GEMM: one staged X tile, two weight sets, interleaved output:
//   out[n*128 + j]      = relu(dot(X[n],Wa[:,j]) + ba[j])
//   out[n*128 + 64 + j] = relu(dot(X[n],Wb[:,j]) + bb[j])
// ---------------------------------------------------------------------------
template<int TR>
__global__ __launch_bounds__(256) void dualgemm_k(
    const float* __restrict__ X, const float* __restrict__ Wa,
    const float* __restrict__ ba, const float* __restrict__ Wb,
    const float* __restrict__ bb, float* __restrict__ out, int N)
{
  __shared__ __align__(16) float sx[TR * H];
  const int n0 = blockIdx.x * TR;
  {
    const float4* X4 = reinterpret_cast<const float4*>(X);
    float4* S4 = reinterpret_cast<float4*>(sx);
    const long base4 = (long)n0 * (H / 4);
    const long lim4 = (long)N * (H / 4);
    for (int i = threadIdx.x; i < TR * H / 4; i += 256)
      S4[i] = (base4 + i < lim4) ? X4[base4 + i] : make_float4(0.f, 0.f, 0.f, 0.f);
  }
  __syncthreads();

  const int lane = threadIdx.x & 63;
  const int wv = threadIdx.x >> 6;
  float wA[H], wB[H];
#pragma unroll
  for (int k = 0; k < H; ++k) { wA[k] = Wa[k * H + lane]; wB[k] = Wb[k * H + lane]; }
  const float bja = ba[lane];
  const float bjb = bb[lane];

  constexpr int RPW = TR / 4;
  const int r0 = wv * RPW;
  for (int i = 0; i < RPW; i += 2) {
    const int na = n0 + r0 + i;
    if (na >= N) break;
    const bool hasB = (na + 1) < N;

    const float4* xa = reinterpret_cast<const float4*>(sx + (r0 + i) * H);
    const float4* xb = reinterpret_cast<const float4*>(sx + (r0 + i + 1) * H);
    float pa0 = 0.f, pa1 = 0.f, pa2 = 0.f, pa3 = 0.f;  // row a, set A
    float pb0 = 0.f, pb1 = 0.f, pb2 = 0.f, pb3 = 0.f;  // row b, set A
    float qa0 = 0.f, qa1 = 0.f, qa2 = 0.f, qa3 = 0.f;  // row a, set B
    float qb0 = 0.f, qb1 = 0.f, qb2 = 0.f, qb3 = 0.f;  // row b, set B
#pragma unroll
    for (int k4 = 0; k4 < H / 4; ++k4) {
      const float4 va = xa[k4];
      const float4 vb = xb[k4];
      pa0 = fmaf(va.x, wA[4 * k4 + 0], pa0);
      pb0 = fmaf(vb.x, wA[4 * k4 + 0], pb0);
      qa0 = fmaf(va.x, wB[4 * k4 + 0], qa0);
      qb0 = fmaf(vb.x, wB[4 * k4 + 0], qb0);
      pa1 = fmaf(va.y, wA[4 * k4 + 1], pa1);
      pb1 = fmaf(vb.y, wA[4 * k4 + 1], pb1);
      qa1 = fmaf(va.y, wB[4 * k4 + 1], qa1);
      qb1 = fmaf(vb.y, wB[4 * k4 + 1], qb1);
      pa2 = fmaf(va.z, wA[4 * k4 + 2], pa2);
      pb2 = fmaf(vb.z, wA[4 * k4 + 2], pb2);
      qa2 = fmaf(va.z, wB[4 * k4 + 2], qa2);
      qb2 = fmaf(vb.z, wB[4 * k4 + 2], qb2);
      pa3 = fmaf(va.w, wA[4 * k4 + 3], pa3);
      pb3 = fmaf(vb.w, wA[4 * k4 + 3], pb3);
      qa3 = fmaf(va.w, wB[4 * k4 + 3], qa3);
      qb3 = fmaf(vb.w, wB[4 * k4 + 3], qb3);
    }
    const float accAa = fmaxf((pa0 + pa1) + (pa2 + pa3) + bja, 0.f);
    const float accAb = fmaxf((qa0 + qa1) + (qa2 + qa3) + bjb, 0.f);
    out[(size_t)na * 128 + lane] = accAa;
    out[(size_t)na * 128 + 64 + lane] = accAb;
    if (hasB) {
      const float accBa = fmaxf((pb0 + pb1) + (pb2 + pb3) + bja, 0.f);
      const float accBb = fmaxf((qb0 + qb1) + (qb2 + qb3) + bjb, 0.f);
      out[(size_t)(na + 1) * 128 + lane] = accBa;
      out[(size_t)(na + 1) * 128 + 64 + lane] = accBb;
    }
  }
}

// ---------------------------------------------------------------------------
// Fused output MLP: z1=relu(x@W+b); z2=relu(z1@W+b); out=z2@Wout+bout.
// ---------------------------------------------------------------------------
template<int TR>
__global__ __launch_bounds__(256) void mlp_k(
    const float* __restrict__ X, const float* __restrict__ W,
    const float* __restrict__ bh, const float* __restrict__ Wout,
    const float* __restrict__ bo, float* __restrict__ out, int N)
{
  __shared__ __align__(16) float sx[TR * H];
  __shared__ __align__(16) float sz[4][H];

  const int n0 = blockIdx.x * TR;
  {
    const float4* X4 = reinterpret_cast<const float4*>(X);
    float4* S4 = reinterpret_cast<float4*>(sx);
    const long base4 = (long)n0 * H / 4;
    const long lim4 = (long)N * H / 4;
    for (int i = threadIdx.x; i < TR * H / 4; i += 256)
      S4[i] = (base4 + i < lim4) ? X4[base4 + i] : make_float4(0.f, 0.f, 0.f, 0.f);
  }
  __syncthreads();

  const int lane = threadIdx.x & 63;
  const int wv = threadIdx.x >> 6;
  float w[H];
#pragma unroll
  for (int k = 0; k < H; ++k) w[k] = W[k * H + lane];
  const float bhl = bh[lane];
  const float wo = Wout[lane];
  const float bol = bo[0];

  constexpr int RPW = TR / 4;
  const int r0 = wv * RPW;
  for (int i = 0; i < RPW; ++i) {
    const int n = n0 + r0 + i;
    if (n >= N) break;
    const float4* x4 = reinterpret_cast<const float4*>(sx + (r0 + i) * H);
    float a0 = 0.f, a1 = 0.f, a2 = 0.f, a3 = 0.f;
#pragma unroll
    for (int k4 = 0; k4 < H / 4; ++k4) {
      const float4 v = x4[k4];
      a0 = fmaf(v.x, w[4 * k4 + 0], a0);
      a1 = fmaf(v.y, w[4 * k4 + 1], a1);
      a2 = fmaf(v.z, w[4 * k4 + 2], a2);
      a3 = fmaf(v.w, w[4 * k4 + 3], a3);
    }
    const float z1 = fmaxf((a0 + a1) + (a2 + a3) + bhl, 0.f);
    sz[wv][lane] = z1;
    const float4* z4 = reinterpret_cast<const float4*>(sz[wv]);
    a0 = 0.f; a1 = 0.f; a2 = 0.f; a3 = 0.f;
#pragma unroll
    for (int k4 = 0; k4 < H / 4; ++k4) {
      const float4 v = z4[k4];
      a0 = fmaf(v.x, w[4 * k4 + 0], a0);
      a1 = fmaf(v.y, w[4 * k4 + 1], a1);
      a2 = fmaf(v.z, w[4 * k4 + 2], a2);
      a3 = fmaf(v.w, w[4 * k4 + 3], a3);
    }
    const float z2 = fmaxf((a0 + a1) + (a2 + a3) + bhl, 0.f);
    float v = z2 * wo;
#pragma unroll
    for (int off = 32; off; off >>= 1) v += __shfl_down(v, off);
    if (lane == 0) out[n] = v + bol;
  }
}

// ---------------------------------------------------------------------------
// Bucketed CSR build: bhist -> bscan -> bscatter -> bfinish (bucket-local
// degree/rowptr/fill in ONE kernel, replacing 5 global passes).
// ---------------------------------------------------------------------------
__global__ __launch_bounds__(256) void bhist_k(const int* __restrict__ key,
                                               int* __restrict__ bcnt, int E, int nb) {
  __shared__ int h[NBMAX];
  for (int i = threadIdx.x; i < nb; i += 256) h[i] = 0;
  __syncthreads();
  const int base = blockIdx.x * EPB;
  for (int i = threadIdx.x; i < EPB; i += 256) {
    const int e = base + i;
    if (e < E) atomicAdd(&h[key[e] >> BSH], 1);
  }
  __syncthreads();
  for (int i = threadIdx.x; i < nb; i += 256)
    if (h[i]) atomicAdd(&bcnt[i], h[i]);
}

__global__ __launch_bounds__(1024) void bscan_k(const int* __restrict__ bcnt,
                                                int* __restrict__ bcur,
                                                int* __restrict__ sbase, int nb) {
  __shared__ int s[1024];
  const int t = threadIdx.x;
  const int v = (t < nb) ? bcnt[t] : 0;
  s[t] = v;
  __syncthreads();
  for (int off = 1; off < 1024; off <<= 1) {
    int x = (t >= off) ? s[t - off] : 0;
    __syncthreads();
    s[t] += x;
    __syncthreads();
  }
  if (t < nb) {
    const int ex = s[t] - v;
    bcur[t] = ex;
    sbase[t] = ex;
    if (t == nb - 1) sbase[nb] = s[t];
  }
}

__global__ __launch_bounds__(256) void bscatter_k(
    const int* __restrict__ key, const int* __restrict__ payload,
    int* __restrict__ bcur, int2* __restrict__ sorted, int E, int nb) {
  __shared__ int h[NBMAX];
  __shared__ int gb[NBMAX];
  __shared__ unsigned short lr[EPB];
  for (int i = threadIdx.x; i < nb; i += 256) h[i] = 0;
  __syncthreads();
  const int base = blockIdx.x * EPB;
  for (int i = threadIdx.x; i < EPB; i += 256) {
    const int e = base + i;
    if (e < E) lr[i] = (unsigned short)atomicAdd(&h[key[e] >> BSH], 1);
  }
  __syncthreads();
  for (int i = threadIdx.x; i < nb; i += 256)
    if (h[i]) gb[i] = atomicAdd(&bcur[i], h[i]);
  __syncthreads();
  for (int i = threadIdx.x; i < EPB; i += 256) {
    const int e = base + i;
    if (e < E) {
      const int k = key[e];
      sorted[gb[k >> BSH] + lr[i]] = make_int2(k, payload[e]);
    }
  }
}

// one block per bucket: LDS degree histogram + scan -> rowptr; LDS-cursor fill
__global__ __launch_bounds__(256) void bfinish_k(
    const int2* __restrict__ sorted, const int* __restrict__ sbase,
    int* __restrict__ rp, int* __restrict__ ei, int Nn) {
  __shared__ int cnt[128];
  __shared__ int scn[128];
  const int b = blockIdx.x;
  const int node0 = b << BSH;
  const int e0 = sbase[b], e1 = sbase[b + 1];
  const int t = threadIdx.x;
  if (t < 128) cnt[t] = 0;
  __syncthreads();
  for (int e = e0 + t; e < e1; e += 256)
    atomicAdd(&cnt[sorted[e].x - node0], 1);
  __syncthreads();
  if (t < 128) scn[t] = cnt[t];
  __syncthreads();
#pragma unroll
  for (int off = 1; off < 128; off <<= 1) {
    int v = (t < 128 && t >= off) ? scn[t - off] : 0;
    __syncthreads();
    if (t < 128) scn[t] += v;  // inclusive scan
    __syncthreads();
  }
  const int nInB = (Nn - node0 < 128) ? (Nn - node0) : 128;
  int myexcl = 0;
  if (t < 128) myexcl = scn[t] - cnt[t];
  if (t < nInB) rp[node0 + t] = e0 + myexcl;
  if (b == (int)gridDim.x - 1 && t == 0) rp[Nn] = e1;
  __syncthreads();
  if (t < 128) cnt[t] = myexcl;  // reuse as cursors
  __syncthreads();
  for (int e = e0 + t; e < e1; e += 256) {
    const int2 kp = sorted[e];
    const int p = atomicAdd(&cnt[kp.x - node0], 1);
    ei[e0 + p] = kp.y;
  }
}

// ---------------------------------------------------------------------------
// Fused dual gather max over interleaved 512B rows [table1 | table2].
// 32 lanes cover one row (float4 each); g = lane>>5 selects edge parity;
// 8 bundles -> 16 edges (8KB) in flight per wave. One wave per dst node.
// ---------------------------------------------------------------------------
__device__ __forceinline__ float4 fmax4(float4 a, float4 b) {
  return make_float4(fmaxf(a.x, b.x), fmaxf(a.y, b.y),
                     fmaxf(a.z, b.z), fmaxf(a.w, b.w));
}

__device__ __forceinline__ float4 gmax2_csr(const float4* __restrict__ t4,
                                            const int* __restrict__ rp,
                                            const int* __restrict__ ei,
                                            int n, int g, int sub) {
  const int p0 = rp[n], p1 = rp[n + 1];
  const float4 z = make_float4(0.f, 0.f, 0.f, 0.f);
  float4 m0 = z, m1 = z, m2 = z, m3 = z, m4 = z, m5 = z, m6 = z, m7 = z;
  if (p1 > p0) {
    const int last = p1 - 1;
    for (int p = p0; p < p1; p += 16) {
      int e0 = p + 0 + g;  e0 = e0 <= last ? e0 : last;
      int e1 = p + 2 + g;  e1 = e1 <= last ? e1 : last;
      int e2 = p + 4 + g;  e2 = e2 <= last ? e2 : last;
      int e3 = p + 6 + g;  e3 = e3 <= last ? e3 : last;
      int e4 = p + 8 + g;  e4 = e4 <= last ? e4 : last;
      int e5 = p + 10 + g; e5 = e5 <= last ? e5 : last;
      int e6 = p + 12 + g; e6 = e6 <= last ? e6 : last;
      int e7 = p + 14 + g; e7 = e7 <= last ? e7 : last;
      const int s0 = ei[e0], s1 = ei[e1], s2 = ei[e2], s3 = ei[e3];
      const int s4 = ei[e4], s5 = ei[e5], s6 = ei[e6], s7 = ei[e7];
      m0 = fmax4(m0, t4[(size_t)s0 * 32 + sub]);
      m1 = fmax4(m1, t4[(size_t)s1 * 32 + sub]);
      m2 = fmax4(m2, t4[(size_t)s2 * 32 + sub]);
      m3 = fmax4(m3, t4[(size_t)s3 * 32 + sub]);
      m4 = fmax4(m4, t4[(size_t)s4 * 32 + sub]);
      m5 = fmax4(m5, t4[(size_t)s5 * 32 + sub]);
      m6 = fmax4(m6, t4[(size_t)s6 * 32 + sub]);
      m7 = fmax4(m7, t4[(size_t)s7 * 32 + sub]);
    }
  }
  float4 m = fmax4(fmax4(fmax4(m0, m1), fmax4(m2, m3)),
                   fmax4(fmax4(m4, m5), fmax4(m6, m7)));
  m.x = fmaxf(m.x, __shfl_xor(m.x, 32));
  m.y = fmaxf(m.y, __shfl_xor(m.y, 32));
  m.z = fmaxf(m.z, __shfl_xor(m.z, 32));
  m.w = fmaxf(m.w, __shfl_xor(m.w, 32));
  return m;
}

// fwd: agg{1,2}[n] = maxVar + maxSoc over interleaved pooled table
__global__ __launch_bounds__(256) void gather2f_k(
    const float4* __restrict__ t4,
    const int* __restrict__ rpCv, const int* __restrict__ eiCv,
    const int* __restrict__ rpCs, const int* __restrict__ eiCs,
    float4* __restrict__ agg1, float4* __restrict__ agg2, int N)
{
  const int lane = threadIdx.x & 63;
  const int g = lane >> 5, sub = lane & 31;
  const int n = __builtin_amdgcn_readfirstlane(blockIdx.x * 4 + (threadIdx.x >> 6));
  if (n >= N) return;
  const float4 a = gmax2_csr(t4, rpCv, eiCv, n, g, sub);
  const float4 b = gmax2_csr(t4 + (size_t)NV * 32, rpCs, eiCs, n, g, sub);
  const float4 r = make_float4(a.x + b.x, a.y + b.y, a.z + b.z, a.w + b.w);
  if (g == 0) {
    if (sub < 16) agg1[(size_t)n * 16 + sub] = r;
    else          agg2[(size_t)n * 16 + (sub - 16)] = r;
  }
}

// bwd: node<NV -> var CSR else soc CSR; rows from interleaved con table
__global__ __launch_bounds__(256) void gathervs2_k(
    const float4* __restrict__ t4,
    const int* __restrict__ rpV, const int* __restrict__ eiV,
    const int* __restrict__ rpS, const int* __restrict__ eiS,
    float4* __restrict__ agg1, float4* __restrict__ agg2)
{
  const int lane = threadIdx.x & 63;
  const int g = lane >> 5, sub = lane & 31;
  const int n = __builtin_amdgcn_readfirstlane(blockIdx.x * 4 + (threadIdx.x >> 6));
  if (n >= NVS) return;
  float4 m;
  if (n < NV) m = gmax2_csr(t4, rpV, eiV, n, g, sub);
  else        m = gmax2_csr(t4, rpS, eiS, n - NV, g, sub);
  if (g == 0) {
    if (sub < 16) agg1[(size_t)n * 16 + sub] = m;
    else          agg2[(size_t)n * 16 + (sub - 16)] = m;
  }
}

extern "C" void kernel_launch(void* const* d_in, const int* in_sizes, int n_in,
                              void* d_out, int out_size, void* d_ws, size_t ws_size,
                              hipStream_t stream) {
  const float* var_x = (const float*)d_in[0];
  const float* con_x = (const float*)d_in[1];
  const float* soc_x = (const float*)d_in[2];
  const float* W_var = (const float*)d_in[3];
  const float* b_var = (const float*)d_in[4];
  const float* W_con = (const float*)d_in[5];
  const float* b_con = (const float*)d_in[6];
  const float* W_soc = (const float*)d_in[7];
  const float* b_soc = (const float*)d_in[8];
  const float* L[4][5];  // L[0]=l1f, L[1]=l1b, L[2]=l2f, L[3]=l2b
  for (int l = 0; l < 4; ++l)
    for (int p = 0; p < 5; ++p)
      L[l][p] = (const float*)d_in[9 + l * 5 + p];
  const float* W_hid = (const float*)d_in[29];
  const float* b_hid = (const float*)d_in[30];
  const float* W_out = (const float*)d_in[31];
  const float* b_out = (const float*)d_in[32];
  const int* vc_src = (const int*)d_in[33];
  const int* vc_dst = (const int*)d_in[34];
  const int* sc_src = (const int*)d_in[35];
  const int* sc_dst = (const int*)d_in[36];

  char* ws = (char*)d_ws;
  const size_t F_VS = (size_t)NVS * H * 4;  // 30.72 MB
  const size_t F_C  = (size_t)NC * H * 4;   // 25.6 MB
  float* hvs   = (float*)(ws);
  float* h_con = (float*)(ws + F_VS);
  float* bufA  = (float*)(ws + F_VS + F_C);            // 2*F_VS: fwd pooled / bwd aggs
  float* bufB  = (float*)(ws + 3 * F_VS + F_C);        // 2*F_C : fwd aggs / bwd pooled
  int2*  sorted = (int2*)bufB;                          // 18.4MB < 2*F_C; dead after builds
  char* csr = ws + 3 * F_VS + 3 * F_C;
  int* rpCv = (int*)(csr);
  int* eiCv = rpCv + (NC + 1);
  int* rpCs = eiCv + EVC;
  int* eiCs = rpCs + (NC + 1);
  int* rpV  = eiCs + ESC;
  int* eiV  = rpV + (NV + 1);
  int* rpS  = eiV + EVC;
  int* eiS  = rpS + (NSOC + 1);
  int* aux  = eiS + ESC;
  int* bcnt[4];
  for (int i = 0; i < 4; ++i) bcnt[i] = aux + i * 1024;
  int* bcur  = aux + 4 * 1024;
  int* sbase = aux + 5 * 1024;  // 1025 ints

  constexpr int TR = 64;
  auto grid_l = [](int n) { return dim3((unsigned)((n + TR - 1) / TR)); };
  auto grid_w = [](int n) { return dim3((unsigned)((n + 3) / 4)); };
  auto grid_b = [](int e) { return dim3((unsigned)((e + EPB - 1) / EPB)); };
  const dim3 B(256);

  float* h_var = hvs;                    // rows [0,NV)
  float* h_soc = hvs + (size_t)NV * H;   // rows [NV,NVS)

  hipMemsetAsync(aux, 0, 4 * 1024 * sizeof(int), stream);  // 4 bcnt arrays

  auto build_csr = [&](const int* key, const int* payload, int E, int Nn,
                       int* rp, int* ei, int bi) {
    const int nb = (Nn + (1 << BSH) - 1) >> BSH;
    bhist_k<<<grid_b(E), B, 0, stream>>>(key, bcnt[bi], E, nb);
    bscan_k<<<dim3(1), dim3(1024), 0, stream>>>(bcnt[bi], bcur, sbase, nb);
    bscatter_k<<<grid_b(E), B, 0, stream>>>(key, payload, bcur, sorted, E, nb);
    bfinish_k<<<dim3((unsigned)nb), B, 0, stream>>>(sorted, sbase, rp, ei, Nn);
  };

  // ---- CSR builds (sorted aliases bufB; done before any gather) ----------
  build_csr(vc_dst, vc_src, EVC, NC, rpCv, eiCv, 0);
  build_csr(sc_dst, sc_src, ESC, NC, rpCs, eiCs, 1);
  build_csr(vc_src, vc_dst, EVC, NV, rpV, eiV, 2);
  build_csr(sc_src, sc_dst, ESC, NSOC, rpS, eiS, 3);

  // ---- embeddings --------------------------------------------------------
  gemm_lds<7, 0, true, TR><<<grid_l(NV), B, 0, stream>>>(var_x, W_var, nullptr, nullptr, b_var, h_var, NV, 1.f);
  gemm_lds<4, 0, true, TR><<<grid_l(NC), B, 0, stream>>>(con_x, W_con, nullptr, nullptr, b_con, h_con, NC, 1.f);
  gemm_lds<6, 0, true, TR><<<grid_l(NSOC), B, 0, stream>>>(soc_x, W_soc, nullptr, nullptr, b_soc, h_soc, NSOC, 1.f);

  // ---- forward: dual pooled GEMM -> fused gather -> 2 in-place updates ----
  float* agg1f = bufB;
  float* agg2f = bufB + (size_t)NC * H;
  dualgemm_k<TR><<<grid_l(NVS), B, 0, stream>>>(hvs, L[0][0], L[0][1], L[2][0], L[2][1], bufA, NVS);
  gather2f_k<<<grid_w(NC), B, 0, stream>>>((const float4*)bufA, rpCv, eiCv, rpCs, eiCs,
                                           (float4*)agg1f, (float4*)agg2f, NC);
  gemm_lds<64, 1, true, TR><<<grid_l(NC), B, 0, stream>>>(h_con, L[0][2], agg1f, L[0][3], L[0][4], h_con, NC, 2.f);
  gemm_lds<64, 1, true, TR><<<grid_l(NC), B, 0, stream>>>(h_con, L[2][2], agg2f, L[2][3], L[2][4], h_con, NC, 2.f);

  // ---- backward: dual pooled GEMM -> fused gather -> 2 in-place updates ---
  float* agg1b = bufA;
  float* agg2b = bufA + (size_t)NVS * H;
  dualgemm_k<TR><<<grid_l(NC), B, 0, stream>>>(h_con, L[1][0], L[1][1], L[3][0], L[3][1], bufB, NC);
  gathervs2_k<<<grid_w(NVS), B, 0, stream>>>((const float4*)bufB, rpV, eiV, rpS, eiS,
                                             (float4*)agg1b, (float4*)agg2b);
  gemm_lds<64, 1, true, TR><<<grid_l(NVS), B, 0, stream>>>(hvs, L[1][2], agg1b, L[1][3], L[1][4], hvs, NVS, 1.f);
  gemm_lds<64, 1, true, TR><<<grid_l(NVS), B, 0, stream>>>(hvs, L[3][2], agg2b, L[3][3], L[3][4], hvs, NVS, 1.f);

  // ---- fused output MLP over var rows ------------------------------------
  mlp_k<TR><<<grid_l(NV), B, 0, stream>>>(hvs, W_hid, b_hid, W_out, b_out, (float*)d_out, NV);
}